// Round 7
// baseline (54.870 us; speedup 1.0000x reference)
//
#include <hip/hip_runtime.h>

// SmoothSkeletonDual, all-register single-wave-tile version.
// T'_0 = exp2(-x*C1); T'_{k+1} = box3x3(T'_k) (unnormalized).
// term_k = clip(-C2*log2(T'_k(p) * sum_{3x3} 1/T'_{k+1}(q)), 0, 1)
// skel = sum_{k=0}^{10} term_k
//
// One wave per 64x64 tile (output 40x40, halo 12). Lane = column (A[64] in
// VGPRs); horizontal neighbors via DPP wave shifts; vertical via register
// rolling. Box + rcp-box + term fused in ONE in-place sweep per iteration.
// No LDS, no barriers. Garbage (DPP zero-fill / stale edge rows) stays in
// the shrinking invalid band: valid [j+1,62-j] contains term needs [11,52]
// for all j<=10 -- halo 12 exactly sufficient.

#define HH 1024
#define WW 1024
#define OT 40              // output tile (both dims)
#define TR 64              // rows held per lane
#define HALO 12
#define NTX 26             // ceil(1024/40)
#define NTILE (NTX*NTX*2)  // 1352 tiles = 1352 waves

constexpr float C1 = 28.85390081777927f;   // 1/(alpha*ln2)
constexpr float C2 = 0.03465735902799726f; // alpha*ln2

__device__ __forceinline__ int mir(int i, int n) {
    return i < 0 ? -i : (i >= n ? 2 * n - 2 - i : i);
}
// lane i <- lane i-1 (WAVE_SHR1 0x138; lane 0 zero-filled)
__device__ __forceinline__ float nbrL(float v) {
    return __int_as_float(__builtin_amdgcn_update_dpp(
        0, __float_as_int(v), 0x138, 0xf, 0xf, true));
}
// lane i <- lane i+1 (WAVE_SHL1 0x130; lane 63 zero-filled)
__device__ __forceinline__ float nbrR(float v) {
    return __int_as_float(__builtin_amdgcn_update_dpp(
        0, __float_as_int(v), 0x130, 0xf, 0xf, true));
}
__device__ __forceinline__ float hsum3(float v) { return nbrL(v) + v + nbrR(v); }
__device__ __forceinline__ float clamp01(float v) { return fminf(fmaxf(v, 0.f), 1.f); }

__global__ __launch_bounds__(64) void skel_k(const float* __restrict__ x0,
                                             float* __restrict__ out) {
    const int lane = threadIdx.x;
    const int t  = blockIdx.x;
    const int tx = t % NTX;
    const int r  = t / NTX;
    const int ty = r % NTX;
    const int b  = r / NTX;

    const float* src = x0 + (size_t)b * HH * WW;
    const int mx  = mir(tx * OT - HALO + lane, WW);
    const int gy0 = ty * OT - HALO;

    // load column: A[y] = exp2(-x * C1), mirror rows/cols
    float A[TR];
    #pragma unroll
    for (int y = 0; y < TR; ++y) {
        int my = mir(gy0 + y, HH);
        A[y] = __builtin_amdgcn_exp2f(src[(size_t)my * WW + mx] * -C1);
    }

    float sk[OT];
    #pragma unroll
    for (int i = 0; i < OT; ++i) sk[i] = 0.f;

    #pragma unroll 1
    for (int j = 0; j < 11; ++j) {
        // in-place sweep: N[y] = vsum(hsum(O[y-1..y+1])); term row y-1 uses
        // P = O[y-1] (pre-overwrite, held in o_m) and rcp-hsums of N[y-2..y].
        float o_m = A[0], o_c = A[1];
        float h_m = hsum3(o_m), h_c = hsum3(o_c);
        float hr2 = 0.f, hr1 = 0.f;
        #pragma unroll
        for (int y = 1; y <= TR - 2; ++y) {
            float o_p = A[y + 1];            // original (overwritten at y+1)
            float h_p = hsum3(o_p);
            float n   = h_m + h_c + h_p;     // N[y]
            float hr0 = 0.f;
            if (y >= 11 && y <= 52)          // rcp-hsum only where needed
                hr0 = hsum3(__builtin_amdgcn_rcpf(n));
            if (y >= 13 && y <= 52)          // term row y-1 in [12,51]
                sk[y - 13] += clamp01(
                    -C2 * __builtin_amdgcn_logf(o_m * (hr2 + hr1 + hr0)));
            A[y] = n;
            o_m = o_c; o_c = o_p;
            h_m = h_c; h_c = h_p;
            hr2 = hr1; hr1 = hr0;
        }
    }

    // write output 40x40 (lanes 12..51, rows 12..51)
    if (lane >= HALO && lane < HALO + OT) {
        int gx = tx * OT + lane - HALO;
        if (gx < WW) {
            float* dst = out + (size_t)b * HH * WW;
            #pragma unroll
            for (int i = 0; i < OT; ++i) {
                int gy = ty * OT + i;
                if (gy < HH) dst[(size_t)gy * WW + gx] = sk[i];
            }
        }
    }
}

extern "C" void kernel_launch(void* const* d_in, const int* in_sizes, int n_in,
                              void* d_out, int out_size, void* d_ws, size_t ws_size,
                              hipStream_t stream) {
    const float* x0 = (const float*)d_in[0];
    float* skel = (float*)d_out;
    skel_k<<<dim3(NTILE, 1, 1), dim3(64, 1, 1), 0, stream>>>(x0, skel);
}

// Round 8
// 36.934 us; speedup vs baseline: 1.4856x; 1.4856x over previous
//
#include <hip/hip_runtime.h>

// SmoothSkeletonDual: exp-domain, register-strip + LDS boundary exchange.
// T'_0 = exp2(-x*C1); T'_{j+1} = box3x3(T'_j) (unnormalized).
// term_j = clip(-C2*log2(T'_j(p) * sum_{3x3} 1/T'_{j+1}(q)), 0, 1)
// skel = sum_{j=0}^{10} term_j
//
// Tile 64 cols x 104 rows (output 40x80, halo 12). 8 waves/block; wave w
// owns 13 rows in registers (lane = column). Horizontal neighbors: DPP
// wave shifts. Vertical halo (2 rows each side): exchanged per iteration
// via a 16 KB double-buffered LDS buffer, one barrier per iteration.

#define HH 1024
#define WW 1024
#define NB 2
#define OTX 40
#define OTY 80
#define TH 104            // OTY + 24
#define RPW 13            // rows per wave
#define NW 8
#define HALO 12
#define GX 26             // ceil(1024/40)
#define GY 13             // ceil(1024/80)

constexpr float C1 = 28.85390081777927f;   // 1/(alpha*ln2)
constexpr float C2 = 0.03465735902799726f; // alpha*ln2

__device__ __forceinline__ int mir(int i, int n) {
    return i < 0 ? -i : (i >= n ? 2 * n - 2 - i : i);
}
// lane i <- lane i-1 (WAVE_SHR1 0x138; lane 0 zero-filled)
__device__ __forceinline__ float nbrL(float v) {
    return __int_as_float(__builtin_amdgcn_update_dpp(
        0, __float_as_int(v), 0x138, 0xf, 0xf, true));
}
// lane i <- lane i+1 (WAVE_SHL1 0x130; lane 63 zero-filled)
__device__ __forceinline__ float nbrR(float v) {
    return __int_as_float(__builtin_amdgcn_update_dpp(
        0, __float_as_int(v), 0x130, 0xf, 0xf, true));
}
__device__ __forceinline__ float hsum3(float v) { return nbrL(v) + v + nbrR(v); }
__device__ __forceinline__ float clamp01(float v) { return fminf(fmaxf(v, 0.f), 1.f); }

__global__ __launch_bounds__(512) void skel_k(const float* __restrict__ x0,
                                              float* __restrict__ out) {
    __shared__ float halo[2][NW][4][64];
    const int lane = threadIdx.x & 63;
    const int w    = threadIdx.x >> 6;
    const int tx = blockIdx.x, ty = blockIdx.y, b = blockIdx.z;
    const int gx0 = tx * OTX - HALO, gy0 = ty * OTY - HALO;
    const int r0 = w * RPW;          // first owned tile-row

    const float* src = x0 + (size_t)b * HH * WW;
    const int mx = mir(gx0 + lane, WW);

    // load owned rows: A[i] = exp2(-x * C1)
    float A[RPW];
    #pragma unroll
    for (int i = 0; i < RPW; ++i) {
        int my = mir(gy0 + r0 + i, HH);
        A[i] = __builtin_amdgcn_exp2f(src[(size_t)my * WW + mx] * -C1);
    }

    float sk[RPW];
    #pragma unroll
    for (int i = 0; i < RPW; ++i) sk[i] = 0.f;

    #pragma unroll 1
    for (int j = 0; j < 11; ++j) {
        const int p = j & 1;
        // exchange boundary rows (O local {0,1,11,12})
        halo[p][w][0][lane] = A[0];
        halo[p][w][1][lane] = A[1];
        halo[p][w][2][lane] = A[11];
        halo[p][w][3][lane] = A[12];
        __syncthreads();
        float hm2 = (w > 0)      ? halo[p][w - 1][2][lane] : 1.0f;  // O[-2]
        float hm1 = (w > 0)      ? halo[p][w - 1][3][lane] : 1.0f;  // O[-1]
        float hp0 = (w < NW - 1) ? halo[p][w + 1][0][lane] : 1.0f;  // O[13]
        float hp1 = (w < NW - 1) ? halo[p][w + 1][1][lane] : 1.0f;  // O[14]

        // rolling sweep, k = -1..13: N[k] = vsum3(hsum3(O[k-1..k+1]));
        // hr[k] = hsum3(rcp(N[k])); term t=k-1 uses O[t], hr[t-1..t+1].
        float h_m = hsum3(hm2);
        float h_c = hsum3(hm1);
        float r_2 = 0.f, r_1 = 0.f;   // hr[k-2], hr[k-1]
        float n_prev = 0.f;           // N[k-1]
        #pragma unroll
        for (int k = -1; k <= RPW; ++k) {
            float oext = (k + 1 <= RPW - 1) ? A[k + 1 < 0 ? 0 : k + 1]
                         : (k + 1 == RPW ? hp0 : hp1);   // O[k+1] (static)
            float h_p = hsum3(oext);
            float n   = h_m + h_c + h_p;                 // N[k]
            float r_0 = hsum3(__builtin_amdgcn_rcpf(n)); // hr[k]
            if (k >= 1) {
                int t = k - 1;                           // term row (local)
                int trow = r0 + t;
                if (trow >= HALO && trow < TH - HALO) {
                    float v = -C2 * __builtin_amdgcn_logf(A[t] * (r_2 + r_1 + r_0));
                    sk[t] += clamp01(v);
                }
                A[t] = n_prev;                           // O[t] <- N[t]
            }
            n_prev = n;
            h_m = h_c; h_c = h_p;
            r_2 = r_1; r_1 = r_0;
        }
        __syncthreads();   // protect halo buffer reuse (parity alternates)
    }

    // store output: lanes 12..51, owned rows in [12, 92)
    if (lane >= HALO && lane < HALO + OTX) {
        int gx = tx * OTX + lane - HALO;
        if (gx < WW) {
            float* dst = out + (size_t)b * HH * WW;
            #pragma unroll
            for (int i = 0; i < RPW; ++i) {
                int trow = r0 + i;
                int gy = gy0 + trow;
                if (trow >= HALO && trow < TH - HALO && gy < HH)
                    dst[(size_t)gy * WW + gx] = sk[i];
            }
        }
    }
}

extern "C" void kernel_launch(void* const* d_in, const int* in_sizes, int n_in,
                              void* d_out, int out_size, void* d_ws, size_t ws_size,
                              hipStream_t stream) {
    const float* x0 = (const float*)d_in[0];
    float* skel = (float*)d_out;
    skel_k<<<dim3(GX, GY, NB), dim3(512, 1, 1), 0, stream>>>(x0, skel);
}